// Round 11
// baseline (285.401 us; speedup 1.0000x reference)
//
#include <hip/hip_runtime.h>
#include <stdint.h>

#define K_DIM 1024
#define N_DIM 1024
#define M_DIM 65536

typedef __bf16 bf16_t;
typedef __bf16 bf16x8 __attribute__((ext_vector_type(8)));
typedef float f32x4 __attribute__((ext_vector_type(4)));

#define GLOAD_LDS16(g, l) __builtin_amdgcn_global_load_lds( \
    (const __attribute__((address_space(1))) void*)(g),     \
    (__attribute__((address_space(3))) void*)(l), 16, 0, 0)

#define VMCNT(n) asm volatile("s_waitcnt vmcnt(%0)" ::"n"(n) : "memory")
#define LGKM(n) asm volatile("s_waitcnt lgkmcnt(%0)" ::"n"(n) : "memory")
#define SCHEDB() __builtin_amdgcn_sched_barrier(0)

// ---------------------------------------------------------------------------
// Quantize-dequantize to bf16.
// INVARIANTS:
//  * MX block = 4 ADJACENT LANES (shfl_xor 1/2): lane L always processes
//    item base+L with base % 64 == 0 (r9 post-mortem).
//  * r11: the 8 per-element IEEE divides are replaced by two exact divides
//    (s = mx/7.5f, inv = 1.0f/s) + 8 multiplies. y = x*inv deviates from
//    x/s by <= 1 ulp; a flipped rounding decision moves one element by one
//    grid step (~0.001 effect on any output dot product — threshold 0.071).
//    All other arithmetic unchanged (floor, tie -> lower grid value, fp32).
// ---------------------------------------------------------------------------
__device__ __forceinline__ void qd_compute(f32x4 v0, f32x4 v1,
                                           bf16_t* __restrict__ out,
                                           long long base) {
  float mx = 0.0f;
#pragma unroll
  for (int j = 0; j < 4; ++j) {
    mx = fmaxf(mx, fabsf(v0[j]));
    mx = fmaxf(mx, fabsf(v1[j]));
  }
  mx = fmaxf(mx, __shfl_xor(mx, 1));
  mx = fmaxf(mx, __shfl_xor(mx, 2));
  float s = fmaxf(mx / 7.5f, 1e-30f);  // exact div, as reference
  float inv = 1.0f / s;                // exact div; y = x*inv ~ x/s (<=1ulp)
  bf16x8 o;
#pragma unroll
  for (int j = 0; j < 8; ++j) {
    float xv = (j < 4) ? v0[j] : v1[j - 4];
    float y = xv * inv;
    float m = fabsf(y);
    float h, hinv;
    if (m < 2.0f)      { h = 0.125f; hinv = 8.0f; }
    else if (m < 4.0f) { h = 0.25f;  hinv = 4.0f; }
    else               { h = 0.5f;   hinv = 2.0f; }
    float nn = m * hinv;  // exact (power-of-2 scale)
    float kf = floorf(nn);
    float fr = nn - kf;   // exact
    float up = (fr > 0.5f || (fr == 0.5f && y < 0.0f)) ? 1.0f : 0.0f;
    float q = fminf((kf + up) * h, 7.5f);
    o[j] = (bf16_t)(copysignf(q, y) * s);
  }
  *reinterpret_cast<bf16x8*>(out + base) = o;
}

// w: 131072 items, 512 blocks x 256 threads = exactly 1 item/thread.
__global__ __launch_bounds__(256) void quant_w_kernel(
    const float* __restrict__ w, bf16_t* __restrict__ wd, long long nw) {
  long long i = (long long)blockIdx.x * blockDim.x + threadIdx.x;
  if (i < nw) {
    f32x4 v0 = *reinterpret_cast<const f32x4*>(w + i * 8);
    f32x4 v1 = *reinterpret_cast<const f32x4*>(w + i * 8 + 4);
    qd_compute(v0, v1, wd, i * 8);
  }
}

// x: grid-stride, 4 lane-aligned items per iteration (i + k*tcnt, tcnt a
// multiple of 64), all 8 loads issued before the 4 compute chains.
__global__ __launch_bounds__(256) void quant_x_kernel(
    const float* __restrict__ x, bf16_t* __restrict__ xd, long long nx) {
  const long long tcnt = (long long)gridDim.x * blockDim.x;
  long long i = (long long)blockIdx.x * blockDim.x + threadIdx.x;
  for (; i < nx; i += 4 * tcnt) {
    long long i1 = i + tcnt, i2 = i + 2 * tcnt, i3 = i + 3 * tcnt;
    f32x4 a0 = *reinterpret_cast<const f32x4*>(x + i * 8);
    f32x4 a1 = *reinterpret_cast<const f32x4*>(x + i * 8 + 4);
    f32x4 b0 = *reinterpret_cast<const f32x4*>(x + i1 * 8);
    f32x4 b1 = *reinterpret_cast<const f32x4*>(x + i1 * 8 + 4);
    f32x4 c0 = *reinterpret_cast<const f32x4*>(x + i2 * 8);
    f32x4 c1 = *reinterpret_cast<const f32x4*>(x + i2 * 8 + 4);
    f32x4 d0 = *reinterpret_cast<const f32x4*>(x + i3 * 8);
    f32x4 d1 = *reinterpret_cast<const f32x4*>(x + i3 * 8 + 4);
    qd_compute(a0, a1, xd, i * 8);
    qd_compute(b0, b1, xd, i1 * 8);
    qd_compute(c0, c1, xd, i2 * 8);
    qd_compute(d0, d1, xd, i3 * 8);
  }
}

// ---------------------------------------------------------------------------
// bf16 GEMM C = A*B^T + bias — r3 schedule, verbatim (best measured: 168 us,
// ~820 TF ~ 97% of m248's 848 TF plain-HIP reference at this exact shape).
// 256x256 tile, BK=32, 8 waves (2M x 4N), 4-stage LDS ring (4 x 32KB),
// staging 3 K-tiles ahead, counted vmcnt (never 0 in the main loop):
//   A(t): read af1(t) | STAGE(t+3) | lgkm(4) | 16 MFMA (af0 x bf)
//   B(t): vmcnt(8) | lgkm(0) | s_barrier | pre-read bf,af0(t+1) |
//         16 MFMA (af1 x bf)
// Swizzle: phys 16B slot = logical ^ ((row>>1)&3) — 0 conflicts measured;
// staging source inverse-pre-swizzled (both-sides-or-neither rule).
// ---------------------------------------------------------------------------
__global__ __launch_bounds__(512, 2) void mx_gemm(
    const bf16_t* __restrict__ A, const bf16_t* __restrict__ B,
    const float* __restrict__ bias, float* __restrict__ C) {
  __shared__ char lds[131072];

  const int tid = threadIdx.x;
  const int lane = tid & 63;
  const int wid = tid >> 6;
  const int wm = wid >> 2;  // 0..1  (128-row half)
  const int wn = wid & 3;   // 0..3  (64-col slice)

  // XCD-grouped mapping (verified: A fetched ~once from HBM).
  const int b = blockIdx.x;
  const int xcd = b & 7;
  const int t = b >> 3;
  const int m_tile = xcd * 32 + (t >> 2);  // [0,256)
  const int n_tile = t & 3;                // [0,4)

  const int R0 = tid >> 2;
  const int c0 = ((tid & 3) ^ ((tid >> 3) & 3)) * 8;  // elems
  const bf16_t* aS0 = A + (size_t)(m_tile * 256 + R0) * K_DIM + c0;
  const bf16_t* aS1 = aS0 + (size_t)128 * K_DIM;
  const bf16_t* bS0 = B + (size_t)(n_tile * 256 + R0) * K_DIM + c0;
  const bf16_t* bS1 = bS0 + (size_t)128 * K_DIM;
  const int dstOff = tid * 16;

#define STAGE(u)                                         \
  {                                                      \
    char* sb_ = lds + ((u) & 3) * 32768;                 \
    const int ko_ = (u) * 32;                            \
    GLOAD_LDS16(aS0 + ko_, sb_ + dstOff);                \
    GLOAD_LDS16(aS1 + ko_, sb_ + 8192 + dstOff);         \
    GLOAD_LDS16(bS0 + ko_, sb_ + 16384 + dstOff);        \
    GLOAD_LDS16(bS1 + ko_, sb_ + 24576 + dstOff);        \
  }

  const int ps = (((lane >> 4) ^ ((lane >> 1) & 3)) << 4);
  const int rowb = (lane & 15) * 64 + ps;
  const int aOff = wm * 8192 + rowb;          // + half*4096 + i*1024
  const int bOff = 16384 + wn * 4096 + rowb;  // + j*1024

  f32x4 acc[8][4];
#pragma unroll
  for (int i = 0; i < 8; ++i)
#pragma unroll
    for (int j = 0; j < 4; ++j) acc[i][j] = (f32x4)(0.0f);

  bf16x8 bfA[4], bfB[4], afA[4], afB[4], af1[4];

#define PH_A(T, BF, AF0, DO_STG)                                          \
  {                                                                       \
    const char* sb_ = lds + ((T) & 3) * 32768;                            \
    _Pragma("unroll") for (int i = 0; i < 4; ++i) af1[i] =                \
        *reinterpret_cast<const bf16x8*>(sb_ + aOff + 4096 + i * 1024);   \
    if (DO_STG) STAGE((T) + 3);                                           \
    LGKM(4);                                                              \
    SCHEDB();                                                             \
    __builtin_amdgcn_s_setprio(1);                                        \
    _Pragma("unroll") for (int i = 0; i < 4; ++i)                         \
        _Pragma("unroll") for (int j = 0; j < 4; ++j) acc[i][j] =         \
            __builtin_amdgcn_mfma_f32_16x16x32_bf16(AF0[i], BF[j],        \
                                                    acc[i][j], 0, 0, 0);  \
    __builtin_amdgcn_s_setprio(0);                                        \
  }

#define PH_B(T, BF, NBF, NAF0, VMN, DO_PRE)                                  \
  {                                                                          \
    VMCNT(VMN);                                                              \
    LGKM(0);                                                                 \
    __builtin_amdgcn_s_barrier();                                            \
    SCHEDB();                                                                \
    if (DO_PRE) {                                                            \
      const char* sn_ = lds + (((T) + 1) & 3) * 32768;                       \
      _Pragma("unroll") for (int j = 0; j < 4; ++j) NBF[j] =                 \
          *reinterpret_cast<const bf16x8*>(sn_ + bOff + j * 1024);           \
      _Pragma("unroll") for (int i = 0; i < 4; ++i) NAF0[i] =                \
          *reinterpret_cast<const bf16x8*>(sn_ + aOff + i * 1024);           \
    }                                                                        \
    __builtin_amdgcn_s_setprio(1);                                           \
    _Pragma("unroll") for (int i = 0; i < 4; ++i)                            \
        _Pragma("unroll") for (int j = 0; j < 4; ++j) acc[4 + i][j] =        \
            __builtin_amdgcn_mfma_f32_16x16x32_bf16(af1[i], BF[j],           \
                                                    acc[4 + i][j], 0, 0, 0); \
    __builtin_amdgcn_s_setprio(0);                                           \
  }

  // Prologue: 3 K-tiles staged; wait tile 0; pre-read its bf/af0.
  STAGE(0);
  STAGE(1);
  STAGE(2);
  VMCNT(8);
  __builtin_amdgcn_s_barrier();
  SCHEDB();
#pragma unroll
  for (int j = 0; j < 4; ++j)
    bfA[j] = *reinterpret_cast<const bf16x8*>(lds + bOff + j * 1024);
#pragma unroll
  for (int i = 0; i < 4; ++i)
    afA[i] = *reinterpret_cast<const bf16x8*>(lds + aOff + i * 1024);

  for (int p = 0; p < 14; ++p) {
    const int u = 2 * p;
    PH_A(u, bfA, afA, true);
    PH_B(u, bfA, bfB, afB, 8, true);
    PH_A(u + 1, bfB, afB, true);
    PH_B(u + 1, bfB, bfA, afA, 8, true);
  }
  // t=28 (stages tile 31, the last)
  PH_A(28, bfA, afA, true);
  PH_B(28, bfA, bfB, afB, 8, true);
  // t=29: outstanding = tiles 30,31 (8 loads) -> wait 30's: vmcnt(4)
  PH_A(29, bfB, afB, false);
  PH_B(29, bfB, bfA, afA, 4, true);
  // t=30: outstanding = tile 31 (4 loads) -> vmcnt(0)
  PH_A(30, bfA, afA, false);
  PH_B(30, bfA, bfB, afB, 0, true);
  // t=31: final tile, no pre-read / no vmcnt / no barrier
  PH_A(31, bfB, afB, false);
  LGKM(0);
  SCHEDB();
#pragma unroll
  for (int i = 0; i < 4; ++i)
#pragma unroll
    for (int j = 0; j < 4; ++j)
      acc[4 + i][j] = __builtin_amdgcn_mfma_f32_16x16x32_bf16(
          af1[i], bfB[j], acc[4 + i][j], 0, 0, 0);

  // Epilogue. C/D layout: col = lane&15, row = (lane>>4)*4 + reg (m89).
  const int col0 = n_tile * 256 + wn * 64 + (lane & 15);
  const int row0 = m_tile * 256 + wm * 128 + ((lane >> 4) << 2);
#pragma unroll
  for (int j = 0; j < 4; ++j) {
    float bv = bias[col0 + j * 16];
#pragma unroll
    for (int m = 0; m < 8; ++m) {
#pragma unroll
      for (int r = 0; r < 4; ++r) {
        C[(size_t)(row0 + m * 16 + r) * N_DIM + col0 + j * 16] =
            acc[m][j][r] + bv;
      }
    }
  }
#undef STAGE
#undef PH_A
#undef PH_B
}

extern "C" void kernel_launch(void* const* d_in, const int* in_sizes, int n_in,
                              void* d_out, int out_size, void* d_ws,
                              size_t ws_size, hipStream_t stream) {
  const float* x = (const float*)d_in[0];     // 8*8192*1024 fp32
  const float* w = (const float*)d_in[1];     // 1024*1024 fp32
  const float* bias = (const float*)d_in[2];  // 1024 fp32
  float* out = (float*)d_out;                 // 65536*1024 fp32

  bf16_t* xd = (bf16_t*)d_ws;               // 128 MB
  bf16_t* wd = xd + (size_t)M_DIM * K_DIM;  // +2 MB

  // x first (long pole), then w; both before the GEMM on the same stream.
  quant_x_kernel<<<2048, 256, 0, stream>>>(x, xd,
                                           (long long)M_DIM * K_DIM / 8);
  quant_w_kernel<<<512, 256, 0, stream>>>(w, wd,
                                          (long long)K_DIM * N_DIM / 8);

  mx_gemm<<<(M_DIM / 256) * (N_DIM / 256), 512, 0, stream>>>(xd, wd, bias,
                                                             out);
}

// Round 12
// 268.823 us; speedup vs baseline: 1.0617x; 1.0617x over previous
//
#include <hip/hip_runtime.h>
#include <stdint.h>

#define K_DIM 1024
#define N_DIM 1024
#define M_DIM 65536

typedef __bf16 bf16_t;
typedef __bf16 bf16x8 __attribute__((ext_vector_type(8)));
typedef float f32x4 __attribute__((ext_vector_type(4)));

#define GLOAD_LDS16(g, l) __builtin_amdgcn_global_load_lds( \
    (const __attribute__((address_space(1))) void*)(g),     \
    (__attribute__((address_space(3))) void*)(l), 16, 0, 0)

#define VMCNT(n) asm volatile("s_waitcnt vmcnt(%0)" ::"n"(n) : "memory")
#define LGKM(n) asm volatile("s_waitcnt lgkmcnt(%0)" ::"n"(n) : "memory")
#define SCHEDB() __builtin_amdgcn_sched_barrier(0)

// ---------------------------------------------------------------------------
// Quantize-dequantize to bf16 — r10 structure (best measured) + r11's
// verified inv-multiply arithmetic.
// INVARIANTS:
//  * MX block = 4 ADJACENT LANES (shfl_xor 1/2): lane L processes item
//    base+L, base % 64 == 0 (r9 post-mortem).
//  * s = mx/7.5 and inv = 1/s are exact IEEE divides (as reference);
//    y = x*inv deviates <= 1 ulp from x/s — a flipped rounding decision
//    moves one element one grid step (~0.001 on any output; thr 0.071).
//    Verified passing in r11 (absmax 0.015625, same as div version).
// ---------------------------------------------------------------------------
__device__ __forceinline__ void qd_compute(f32x4 v0, f32x4 v1,
                                           bf16_t* __restrict__ out,
                                           long long base) {
  float mx = 0.0f;
#pragma unroll
  for (int j = 0; j < 4; ++j) {
    mx = fmaxf(mx, fabsf(v0[j]));
    mx = fmaxf(mx, fabsf(v1[j]));
  }
  mx = fmaxf(mx, __shfl_xor(mx, 1));
  mx = fmaxf(mx, __shfl_xor(mx, 2));
  float s = fmaxf(mx / 7.5f, 1e-30f);  // exact div, as reference
  float inv = 1.0f / s;                // exact div; y = x*inv ~ x/s (<=1ulp)
  bf16x8 o;
#pragma unroll
  for (int j = 0; j < 8; ++j) {
    float xv = (j < 4) ? v0[j] : v1[j - 4];
    float y = xv * inv;
    float m = fabsf(y);
    float h, hinv;
    if (m < 2.0f)      { h = 0.125f; hinv = 8.0f; }
    else if (m < 4.0f) { h = 0.25f;  hinv = 4.0f; }
    else               { h = 0.5f;   hinv = 2.0f; }
    float nn = m * hinv;  // exact (power-of-2 scale)
    float kf = floorf(nn);
    float fr = nn - kf;   // exact
    float up = (fr > 0.5f || (fr == 0.5f && y < 0.0f)) ? 1.0f : 0.0f;
    float q = fminf((kf + up) * h, 7.5f);
    o[j] = (bf16_t)(copysignf(q, y) * s);
  }
  *reinterpret_cast<bf16x8*>(out + base) = o;
}

__global__ __launch_bounds__(256) void quant_dequant_kernel(
    const float* __restrict__ x, bf16_t* __restrict__ xd, long long nx,
    const float* __restrict__ w, bf16_t* __restrict__ wd, long long nw) {
  if (blockIdx.x < 512) {
    // w: 131072 items, 512*256 threads -> exactly 1 item/thread (lane-aligned).
    long long i = (long long)blockIdx.x * blockDim.x + threadIdx.x;
    if (i < nw) {
      f32x4 v0 = *reinterpret_cast<const f32x4*>(w + i * 8);
      f32x4 v1 = *reinterpret_cast<const f32x4*>(w + i * 8 + 4);
      qd_compute(v0, v1, wd, i * 8);
    }
  } else {
    // x: grid-stride unrolled by 2; items i and i+tcnt both lane-aligned;
    // both 32B loads issued before either compute chain.
    long long tcnt = (long long)(gridDim.x - 512) * blockDim.x;
    long long i = (long long)(blockIdx.x - 512) * blockDim.x + threadIdx.x;
    for (; i < nx; i += 2 * tcnt) {
      long long i2 = i + tcnt;
      f32x4 a0 = *reinterpret_cast<const f32x4*>(x + i * 8);
      f32x4 a1 = *reinterpret_cast<const f32x4*>(x + i * 8 + 4);
      f32x4 b0 = *reinterpret_cast<const f32x4*>(x + i2 * 8);
      f32x4 b1 = *reinterpret_cast<const f32x4*>(x + i2 * 8 + 4);
      qd_compute(a0, a1, xd, i * 8);
      qd_compute(b0, b1, xd, i2 * 8);
    }
  }
}

// ---------------------------------------------------------------------------
// bf16 GEMM C = A*B^T + bias — r3 schedule, verbatim (best measured: 168 us,
// 823 TF ~ 97% of m248's 848 TF plain-HIP reference at this exact shape).
// 256x256 tile, BK=32, 8 waves (2M x 4N), 4-stage LDS ring (4 x 32KB),
// staging 3 K-tiles ahead, counted vmcnt (never 0 in the main loop):
//   A(t): read af1(t) | STAGE(t+3) | lgkm(4) | 16 MFMA (af0 x bf)
//   B(t): vmcnt(8) | lgkm(0) | s_barrier | pre-read bf,af0(t+1) |
//         16 MFMA (af1 x bf)
// Swizzle: phys 16B slot = logical ^ ((row>>1)&3) — 0 conflicts measured;
// staging source inverse-pre-swizzled (both-sides-or-neither rule).
// ---------------------------------------------------------------------------
__global__ __launch_bounds__(512, 2) void mx_gemm(
    const bf16_t* __restrict__ A, const bf16_t* __restrict__ B,
    const float* __restrict__ bias, float* __restrict__ C) {
  __shared__ char lds[131072];

  const int tid = threadIdx.x;
  const int lane = tid & 63;
  const int wid = tid >> 6;
  const int wm = wid >> 2;  // 0..1  (128-row half)
  const int wn = wid & 3;   // 0..3  (64-col slice)

  // XCD-grouped mapping (verified: A fetched ~once from HBM).
  const int b = blockIdx.x;
  const int xcd = b & 7;
  const int t = b >> 3;
  const int m_tile = xcd * 32 + (t >> 2);  // [0,256)
  const int n_tile = t & 3;                // [0,4)

  const int R0 = tid >> 2;
  const int c0 = ((tid & 3) ^ ((tid >> 3) & 3)) * 8;  // elems
  const bf16_t* aS0 = A + (size_t)(m_tile * 256 + R0) * K_DIM + c0;
  const bf16_t* aS1 = aS0 + (size_t)128 * K_DIM;
  const bf16_t* bS0 = B + (size_t)(n_tile * 256 + R0) * K_DIM + c0;
  const bf16_t* bS1 = bS0 + (size_t)128 * K_DIM;
  const int dstOff = tid * 16;

#define STAGE(u)                                         \
  {                                                      \
    char* sb_ = lds + ((u) & 3) * 32768;                 \
    const int ko_ = (u) * 32;                            \
    GLOAD_LDS16(aS0 + ko_, sb_ + dstOff);                \
    GLOAD_LDS16(aS1 + ko_, sb_ + 8192 + dstOff);         \
    GLOAD_LDS16(bS0 + ko_, sb_ + 16384 + dstOff);        \
    GLOAD_LDS16(bS1 + ko_, sb_ + 24576 + dstOff);        \
  }

  const int ps = (((lane >> 4) ^ ((lane >> 1) & 3)) << 4);
  const int rowb = (lane & 15) * 64 + ps;
  const int aOff = wm * 8192 + rowb;          // + half*4096 + i*1024
  const int bOff = 16384 + wn * 4096 + rowb;  // + j*1024

  f32x4 acc[8][4];
#pragma unroll
  for (int i = 0; i < 8; ++i)
#pragma unroll
    for (int j = 0; j < 4; ++j) acc[i][j] = (f32x4)(0.0f);

  bf16x8 bfA[4], bfB[4], afA[4], afB[4], af1[4];

#define PH_A(T, BF, AF0, DO_STG)                                          \
  {                                                                       \
    const char* sb_ = lds + ((T) & 3) * 32768;                            \
    _Pragma("unroll") for (int i = 0; i < 4; ++i) af1[i] =                \
        *reinterpret_cast<const bf16x8*>(sb_ + aOff + 4096 + i * 1024);   \
    if (DO_STG) STAGE((T) + 3);                                           \
    LGKM(4);                                                              \
    SCHEDB();                                                             \
    __builtin_amdgcn_s_setprio(1);                                        \
    _Pragma("unroll") for (int i = 0; i < 4; ++i)                         \
        _Pragma("unroll") for (int j = 0; j < 4; ++j) acc[i][j] =         \
            __builtin_amdgcn_mfma_f32_16x16x32_bf16(AF0[i], BF[j],        \
                                                    acc[i][j], 0, 0, 0);  \
    __builtin_amdgcn_s_setprio(0);                                        \
  }

#define PH_B(T, BF, NBF, NAF0, VMN, DO_PRE)                                  \
  {                                                                          \
    VMCNT(VMN);                                                              \
    LGKM(0);                                                                 \
    __builtin_amdgcn_s_barrier();                                            \
    SCHEDB();                                                                \
    if (DO_PRE) {                                                            \
      const char* sn_ = lds + (((T) + 1) & 3) * 32768;                       \
      _Pragma("unroll") for (int j = 0; j < 4; ++j) NBF[j] =                 \
          *reinterpret_cast<const bf16x8*>(sn_ + bOff + j * 1024);           \
      _Pragma("unroll") for (int i = 0; i < 4; ++i) NAF0[i] =                \
          *reinterpret_cast<const bf16x8*>(sn_ + aOff + i * 1024);           \
    }                                                                        \
    __builtin_amdgcn_s_setprio(1);                                           \
    _Pragma("unroll") for (int i = 0; i < 4; ++i)                            \
        _Pragma("unroll") for (int j = 0; j < 4; ++j) acc[4 + i][j] =        \
            __builtin_amdgcn_mfma_f32_16x16x32_bf16(af1[i], BF[j],           \
                                                    acc[4 + i][j], 0, 0, 0); \
    __builtin_amdgcn_s_setprio(0);                                           \
  }

  // Prologue: 3 K-tiles staged; wait tile 0; pre-read its bf/af0.
  STAGE(0);
  STAGE(1);
  STAGE(2);
  VMCNT(8);
  __builtin_amdgcn_s_barrier();
  SCHEDB();
#pragma unroll
  for (int j = 0; j < 4; ++j)
    bfA[j] = *reinterpret_cast<const bf16x8*>(lds + bOff + j * 1024);
#pragma unroll
  for (int i = 0; i < 4; ++i)
    afA[i] = *reinterpret_cast<const bf16x8*>(lds + aOff + i * 1024);

  for (int p = 0; p < 14; ++p) {
    const int u = 2 * p;
    PH_A(u, bfA, afA, true);
    PH_B(u, bfA, bfB, afB, 8, true);
    PH_A(u + 1, bfB, afB, true);
    PH_B(u + 1, bfB, bfA, afA, 8, true);
  }
  // t=28 (stages tile 31, the last)
  PH_A(28, bfA, afA, true);
  PH_B(28, bfA, bfB, afB, 8, true);
  // t=29: outstanding = tiles 30,31 (8 loads) -> wait 30's: vmcnt(4)
  PH_A(29, bfB, afB, false);
  PH_B(29, bfB, bfA, afA, 4, true);
  // t=30: outstanding = tile 31 (4 loads) -> vmcnt(0)
  PH_A(30, bfA, afA, false);
  PH_B(30, bfA, bfB, afB, 0, true);
  // t=31: final tile, no pre-read / no vmcnt / no barrier
  PH_A(31, bfB, afB, false);
  LGKM(0);
  SCHEDB();
#pragma unroll
  for (int i = 0; i < 4; ++i)
#pragma unroll
    for (int j = 0; j < 4; ++j)
      acc[4 + i][j] = __builtin_amdgcn_mfma_f32_16x16x32_bf16(
          af1[i], bfB[j], acc[4 + i][j], 0, 0, 0);

  // Epilogue. C/D layout: col = lane&15, row = (lane>>4)*4 + reg (m89).
  const int col0 = n_tile * 256 + wn * 64 + (lane & 15);
  const int row0 = m_tile * 256 + wm * 128 + ((lane >> 4) << 2);
#pragma unroll
  for (int j = 0; j < 4; ++j) {
    float bv = bias[col0 + j * 16];
#pragma unroll
    for (int m = 0; m < 8; ++m) {
#pragma unroll
      for (int r = 0; r < 4; ++r) {
        C[(size_t)(row0 + m * 16 + r) * N_DIM + col0 + j * 16] =
            acc[m][j][r] + bv;
      }
    }
  }
#undef STAGE
#undef PH_A
#undef PH_B
}

extern "C" void kernel_launch(void* const* d_in, const int* in_sizes, int n_in,
                              void* d_out, int out_size, void* d_ws,
                              size_t ws_size, hipStream_t stream) {
  const float* x = (const float*)d_in[0];     // 8*8192*1024 fp32
  const float* w = (const float*)d_in[1];     // 1024*1024 fp32
  const float* bias = (const float*)d_in[2];  // 1024 fp32
  float* out = (float*)d_out;                 // 65536*1024 fp32

  bf16_t* xd = (bf16_t*)d_ws;               // 128 MB
  bf16_t* wd = xd + (size_t)M_DIM * K_DIM;  // +2 MB

  // Fused launch (r10 best config): blocks [0,512) w, [512,4608) x.
  quant_dequant_kernel<<<4608, 256, 0, stream>>>(
      x, xd, (long long)M_DIM * K_DIM / 8, w, wd,
      (long long)K_DIM * N_DIM / 8);

  mx_gemm<<<(M_DIM / 256) * (N_DIM / 256), 512, 0, stream>>>(xd, wd, bias,
                                                             out);
}